// Round 5
// baseline (615.455 us; speedup 1.0000x reference)
//
#include <hip/hip_runtime.h>
#include <stdint.h>

// TT-stack: out[b][(a,c,d)][(i,j,l)] = sum_{k,m} c0[s][a,i,k] c1[s][k,c,j,m] c2[s][m,d,l]
// R5: latency-focused restructure of the R4 kernel (R4 kernel ~236us):
//  - NO LDS staging for c1/c2: c1 read fp32 direct from L2 (kills bf16 pack+unpack
//    ~580 VALU ops/thread and 36KB LDS); c2 hi/lo A-fragments built in registers.
//  - Wave-private t (rows wv*128..wv*128+127 written and read by wave wv only)
//    => ZERO barriers (pattern HW-validated in R1/R2).
//  - LDS 16KB, __launch_bounds__(256,4) => 4 blocks/CU, 16 waves/CU (was 3/12).
//  - XCD-grouping: b = bid&511, a = bid>>9 -> all 8 a-blocks of b on one XCD,
//    c1 slice L3->L2 once, 7x L2 hits; 64 slices/XCD = 4MB = L2 size.
//  - Step2 MFMA epilogue unchanged from R4 (HW-validated): A=c2 hi|lo in K=32,
//    B=t m-duplicated, D rows=(d,l) -> contiguous nontemporal float4 stores.

typedef short short8 __attribute__((ext_vector_type(8)));
typedef float f32x4 __attribute__((ext_vector_type(4)));

__device__ __forceinline__ uint32_t pack_bf2(float f0, float f1) {
  uint32_t a = __float_as_uint(f0) + 0x8000u;
  uint32_t b = __float_as_uint(f1) + 0x8000u;
  return (a >> 16) | (b & 0xffff0000u);
}

__global__ __launch_bounds__(256, 4) void tt_stack_kernel(
    const float* __restrict__ c0f,
    const float* __restrict__ c1f,
    const float* __restrict__ c2f,
    const int* __restrict__ idx,
    float* __restrict__ outf)
{
  __shared__ __align__(16) uint32_t lds_t[4096];  // bf16 [row=512][m=16] half-swz 16KB

  const int tid = threadIdx.x;
  const int bid = blockIdx.x;
  const int b = bid & 511;   // XCD-group: 8 a-blocks of b share an XCD (512%8==0)
  const int a = bid >> 9;
  const int s = idx[b];
  const size_t s1024 = (size_t)s * 1024;

  const int lane = tid & 63, wv = tid >> 6;
  const int g = lane >> 4, lcol = lane & 15;

  // ---- A-fragments: c2 -> hi/lo bf16 over K=32, direct global->regs ----
  // lane(g,lcol) rt: A row=(d,l)=rt*16+lcol, kk=g*8+e:
  //   kk 0..15 = hi(m=kk), kk 16..31 = lo(m=kk-16); m = (g&1)*8+e.
  short8 Afr[4];
  {
    const float* c2s = c2f + s1024 + (size_t)((g & 1) * 8) * 64;
#pragma unroll
    for (int rt = 0; rt < 4; ++rt) {
      const int col = rt * 16 + lcol;
      uint32_t w[4];
#pragma unroll
      for (int p = 0; p < 4; ++p) {
        const float v0 = c2s[(2 * p) * 64 + col];
        const float v1 = c2s[(2 * p + 1) * 64 + col];
        const uint32_t h0 = (__float_as_uint(v0) + 0x8000u) & 0xffff0000u;
        const uint32_t h1 = (__float_as_uint(v1) + 0x8000u) & 0xffff0000u;
        const uint32_t hip = (h0 >> 16) | h1;
        const uint32_t lop = pack_bf2(v0 - __uint_as_float(h0),
                                      v1 - __uint_as_float(h1));
        w[p] = (g < 2) ? hip : lop;
      }
      uint4 wq = make_uint4(w[0], w[1], w[2], w[3]);
      Afr[rt] = *reinterpret_cast<short8*>(&wq);
    }
  }

  // ---- c0 row (i fixed per lane): 16 fp32 in regs, direct global ----
  const int i = (lane >> 3) & 7, j = lane & 7;
  float c0v[16];
  {
    const float* c0s = c0f + (size_t)(s * 8 + a) * 128 + i * 16;
#pragma unroll
    for (int q = 0; q < 4; ++q)
      *(f32x4*)&c0v[q * 4] = *(const f32x4*)(c0s + q * 4);
  }

  const int sw = (lane >> 2) & 1;                 // t half-swap key (row bit 2)
  const int hsel = (g & 1) ^ ((lcol >> 2) & 1);   // read-side key
  float* const outa = outf + (size_t)b * 262144 + a * 32768;

  // ---- step 1: t rows wv*128+cc*64+lane; c1 fp32 direct from L2 ----
#pragma unroll
  for (int cc = 0; cc < 2; ++cc) {
    const int row = wv * 128 + cc * 64 + lane;    // (c,i,j), c = wv*2+cc
    const int c = wv * 2 + cc;
    const float* c1r = c1f + (size_t)s * 16384 + (size_t)(c * 8 + j) * 16;
    float acc[16];
#pragma unroll
    for (int m = 0; m < 16; ++m) acc[m] = 0.f;
#pragma unroll 2
    for (int k = 0; k < 16; ++k) {
      const f32x4* rp = (const f32x4*)(c1r + (size_t)k * 1024);
      const f32x4 v0 = rp[0];
      const f32x4 v1 = rp[1];
      const f32x4 v2 = rp[2];
      const f32x4 v3 = rp[3];
      const float av = c0v[k];
      acc[0]  = fmaf(av, v0[0], acc[0]);   acc[1]  = fmaf(av, v0[1], acc[1]);
      acc[2]  = fmaf(av, v0[2], acc[2]);   acc[3]  = fmaf(av, v0[3], acc[3]);
      acc[4]  = fmaf(av, v1[0], acc[4]);   acc[5]  = fmaf(av, v1[1], acc[5]);
      acc[6]  = fmaf(av, v1[2], acc[6]);   acc[7]  = fmaf(av, v1[3], acc[7]);
      acc[8]  = fmaf(av, v2[0], acc[8]);   acc[9]  = fmaf(av, v2[1], acc[9]);
      acc[10] = fmaf(av, v2[2], acc[10]);  acc[11] = fmaf(av, v2[3], acc[11]);
      acc[12] = fmaf(av, v3[0], acc[12]);  acc[13] = fmaf(av, v3[1], acc[13]);
      acc[14] = fmaf(av, v3[2], acc[14]);  acc[15] = fmaf(av, v3[3], acc[15]);
    }
    // write own t row; m-halves swapped when (row>>2)&1 (read side undoes)
    uint32_t* tb = &lds_t[row * 8];
    *(uint4*)&tb[sw * 4] =
        make_uint4(pack_bf2(acc[0], acc[1]),  pack_bf2(acc[2], acc[3]),
                   pack_bf2(acc[4], acc[5]),  pack_bf2(acc[6], acc[7]));
    *(uint4*)&tb[4 - sw * 4] =
        make_uint4(pack_bf2(acc[8], acc[9]),  pack_bf2(acc[10], acc[11]),
                   pack_bf2(acc[12], acc[13]), pack_bf2(acc[14], acc[15]));
  }
  // NO barrier: wave wv reads only rows wv*128..wv*128+127 (its own writes);
  // DS ops are in-order per wave, compiler inserts lgkmcnt for same-array dep.

  // ---- step 2: D[(d,l)][(c,i,j)] = c2 @ t via mfma(A=c2, B=t) ----
#pragma unroll
  for (int ctl = 0; ctl < 8; ++ctl) {
    const int cix = wv * 128 + ctl * 16 + lcol;   // B col = (c,i,j), wave-private
    const short8 bv8 = *(const short8*)&lds_t[cix * 8 + hsel * 4];
    const int cq = cix >> 6;      // c
    const int klo = cix & 63;     // (i, j)
    // row = cq*8 + d, d = rt*2 + (g>>1); col floats = klo*8 + (g&1)*4 + reg
    float* const op0 = outa + (size_t)(cq * 8 + (g >> 1)) * 512
                            + klo * 8 + (g & 1) * 4;
#pragma unroll
    for (int rt = 0; rt < 4; ++rt) {
      f32x4 dd = {0.f, 0.f, 0.f, 0.f};
      dd = __builtin_amdgcn_mfma_f32_16x16x32_bf16(Afr[rt], bv8, dd, 0, 0, 0);
      __builtin_nontemporal_store(dd, (f32x4*)(op0 + rt * 1024));
    }
  }
}

extern "C" void kernel_launch(void* const* d_in, const int* in_sizes, int n_in,
                              void* d_out, int out_size, void* d_ws, size_t ws_size,
                              hipStream_t stream) {
  const float* c0f = (const float*)d_in[0];
  const float* c1f = (const float*)d_in[1];
  const float* c2f = (const float*)d_in[2];
  const int* idx = (const int*)d_in[3];
  float* outf = (float*)d_out;
  const int B = in_sizes[3];  // 512
  dim3 grid(B * 8), block(256);
  hipLaunchKernelGGL(tt_stack_kernel, grid, block, 0, stream, c0f, c1f, c2f, idx, outf);
}

// Round 6
// 574.106 us; speedup vs baseline: 1.0720x; 1.0720x over previous
//
#include <hip/hip_runtime.h>
#include <stdint.h>

// TT-stack: out[b][(a,c,d)][(i,j,l)] = sum_{k,m} c0[s][a,i,k] c1[s][k,c,j,m] c2[s][m,d,l]
// R6 = R4 (proven 236us kernel) + occupancy/latency work:
//  - lds_c0/lds_c2b dropped: c0 row and c2 hi/lo A-fragments built in registers
//    direct from global (R5-validated construction, bit-identical absmax).
//  - t is wave-private PER C-HALF: 64 rows x 32B = 2KB/wave, reused for
//    c=wv*2 (h=0) and c=wv*2+1 (h=1). LDS = 32KB c1 + 8KB t = 40KB
//    => 4 blocks/CU (was 3 at 52.5KB). Step1(half) -> step2(half) interleaved;
//    stores of half 0 drain under VALU of half 1.
//  - ONE barrier total (after c1 staging). Wave-private t needs none
//    (per-wave DS in-order; RAW+WAR pattern HW-validated in R1/R2).
//  - Step2 MFMA epilogue unchanged (R2/R4-validated): A=c2 hi|lo in K=32,
//    B=t m-duplicated via half-swap swizzle, D rows=(d,l) -> contiguous
//    nontemporal float4 stores (2x512B dense segments per wave-instr).

typedef short short8 __attribute__((ext_vector_type(8)));
typedef float f32x4 __attribute__((ext_vector_type(4)));

__device__ __forceinline__ float bflo(uint32_t u) { return __uint_as_float(u << 16); }
__device__ __forceinline__ float bfhi(uint32_t u) { return __uint_as_float(u & 0xffff0000u); }
__device__ __forceinline__ uint32_t pack_bf2(float f0, float f1) {
  uint32_t a = __float_as_uint(f0) + 0x8000u;
  uint32_t b = __float_as_uint(f1) + 0x8000u;
  return (a >> 16) | (b & 0xffff0000u);
}

__global__ __launch_bounds__(256, 4) void tt_stack_kernel(
    const float* __restrict__ c0f,
    const float* __restrict__ c1f,
    const float* __restrict__ c2f,
    const int* __restrict__ idx,
    float* __restrict__ outf)
{
  __shared__ __align__(16) uint32_t lds_c1[8192];  // bf16 pairs [k][c][j][m/2] 32 KB
  __shared__ __align__(16) uint32_t lds_t[2048];   // 4 waves x 64 rows x 8      8 KB

  const int tid = threadIdx.x;
  const int bid = blockIdx.x;
  const int b = bid >> 3;        // R4 mapping (proven)
  const int a = bid & 7;
  const int s = idx[b];
  const size_t s1024 = (size_t)s * 1024;

  const int lane = tid & 63, wv = tid >> 6;
  const int g = lane >> 4, lcol = lane & 15;

  // ---- stage c1: fp32 global -> bf16 pairs in LDS, coalesced float4 (R4) ----
  {
    const float4* src4 = (const float4*)(c1f + (size_t)s * 16384);
#pragma unroll
    for (int r = 0; r < 16; ++r) {
      const float4 v = src4[r * 256 + tid];
      uint2* dst = (uint2*)&lds_c1[2 * (r * 256 + tid)];
      *dst = make_uint2(pack_bf2(v.x, v.y), pack_bf2(v.z, v.w));
    }
  }

  // ---- A-fragments: c2 -> hi/lo bf16 over K=32, global->regs (R5-validated) ----
  // lane(g,lcol), rt: A row=(d,l)=rt*16+lcol, kk=g*8+e:
  //   kk 0..15 = hi(m=kk), kk 16..31 = lo(m=kk-16); m = (g&1)*8+e.
  short8 Afr[4];
  {
    const float* c2s = c2f + s1024 + (size_t)((g & 1) * 8) * 64;
#pragma unroll
    for (int rt = 0; rt < 4; ++rt) {
      const int col = rt * 16 + lcol;
      uint32_t w[4];
#pragma unroll
      for (int p = 0; p < 4; ++p) {
        const float v0 = c2s[(2 * p) * 64 + col];
        const float v1 = c2s[(2 * p + 1) * 64 + col];
        const uint32_t h0 = (__float_as_uint(v0) + 0x8000u) & 0xffff0000u;
        const uint32_t h1 = (__float_as_uint(v1) + 0x8000u) & 0xffff0000u;
        const uint32_t hip = (h0 >> 16) | h1;
        const uint32_t lop = pack_bf2(v0 - __uint_as_float(h0),
                                      v1 - __uint_as_float(h1));
        w[p] = (g < 2) ? hip : lop;
      }
      uint4 wq = make_uint4(w[0], w[1], w[2], w[3]);
      Afr[rt] = *reinterpret_cast<short8*>(&wq);
    }
  }

  // ---- c0 row (i fixed per lane): 16 fp32 in regs, global (R5-validated) ----
  const int i = (lane >> 3) & 7, j = lane & 7;
  float c0v[16];
  {
    const float* c0s = c0f + (size_t)(s * 8 + a) * 128 + i * 16;
#pragma unroll
    for (int q = 0; q < 4; ++q)
      *(f32x4*)&c0v[q * 4] = *(const f32x4*)(c0s + q * 4);
  }
  __syncthreads();  // the only barrier (c1 staged)

  const int sw = (lane >> 2) & 1;                 // t half-swap key (row bit 2)
  const int hsel = (g & 1) ^ ((lcol >> 2) & 1);   // read-side key
  uint32_t* const tbuf = &lds_t[wv * 512];        // wave-private 64 rows x 8
  float* const outa = outf + (size_t)b * 262144 + a * 32768;

#pragma unroll
  for (int h = 0; h < 2; ++h) {
    const int c = wv * 2 + h;
    // ---- step 1: t[row=lane=(i,j)][m] = sum_k c0[i,k] * c1[k,c,j,m] ----
    float acc[16];
#pragma unroll
    for (int m = 0; m < 16; ++m) acc[m] = 0.f;
#pragma unroll
    for (int k = 0; k < 16; ++k) {
      const uint4* rp = (const uint4*)&lds_c1[((k * 8 + c) * 8 + j) * 8];
      const uint4 u0 = rp[0];
      const uint4 u1 = rp[1];
      const float av = c0v[k];
      acc[0]  = fmaf(av, bflo(u0.x), acc[0]);   acc[1]  = fmaf(av, bfhi(u0.x), acc[1]);
      acc[2]  = fmaf(av, bflo(u0.y), acc[2]);   acc[3]  = fmaf(av, bfhi(u0.y), acc[3]);
      acc[4]  = fmaf(av, bflo(u0.z), acc[4]);   acc[5]  = fmaf(av, bfhi(u0.z), acc[5]);
      acc[6]  = fmaf(av, bflo(u0.w), acc[6]);   acc[7]  = fmaf(av, bfhi(u0.w), acc[7]);
      acc[8]  = fmaf(av, bflo(u1.x), acc[8]);   acc[9]  = fmaf(av, bfhi(u1.x), acc[9]);
      acc[10] = fmaf(av, bflo(u1.y), acc[10]);  acc[11] = fmaf(av, bfhi(u1.y), acc[11]);
      acc[12] = fmaf(av, bflo(u1.z), acc[12]);  acc[13] = fmaf(av, bfhi(u1.z), acc[13]);
      acc[14] = fmaf(av, bflo(u1.w), acc[14]);  acc[15] = fmaf(av, bfhi(u1.w), acc[15]);
    }
    // write own t row (local row = lane); m-halves swapped when lane bit2 set
    *(uint4*)&tbuf[lane * 8 + sw * 4] =
        make_uint4(pack_bf2(acc[0], acc[1]),  pack_bf2(acc[2], acc[3]),
                   pack_bf2(acc[4], acc[5]),  pack_bf2(acc[6], acc[7]));
    *(uint4*)&tbuf[lane * 8 + 4 - sw * 4] =
        make_uint4(pack_bf2(acc[8], acc[9]),  pack_bf2(acc[10], acc[11]),
                   pack_bf2(acc[12], acc[13]), pack_bf2(acc[14], acc[15]));
    // no barrier: wave reads only its own 64 rows (per-wave DS in-order)

    // ---- step 2: D[(d,l)][(c,i,j)] = c2 @ t for this c-half ----
#pragma unroll
    for (int ctl = 0; ctl < 4; ++ctl) {
      const int r = ctl * 16 + lcol;             // local row = (i,j) col index
      const short8 bv8 = *(const short8*)&tbuf[r * 8 + hsel * 4];
      // out row = c*8 + d, d = rt*2 + (g>>1); col floats = r*8 + (g&1)*4 + reg
      float* const op0 = outa + (size_t)(c * 8 + (g >> 1)) * 512
                              + r * 8 + (g & 1) * 4;
#pragma unroll
      for (int rt = 0; rt < 4; ++rt) {
        f32x4 dd = {0.f, 0.f, 0.f, 0.f};
        dd = __builtin_amdgcn_mfma_f32_16x16x32_bf16(Afr[rt], bv8, dd, 0, 0, 0);
        __builtin_nontemporal_store(dd, (f32x4*)(op0 + rt * 1024));
      }
    }
    // next half: same wave overwrites its own t rows (WAR safe per-wave)
  }
}

extern "C" void kernel_launch(void* const* d_in, const int* in_sizes, int n_in,
                              void* d_out, int out_size, void* d_ws, size_t ws_size,
                              hipStream_t stream) {
  const float* c0f = (const float*)d_in[0];
  const float* c1f = (const float*)d_in[1];
  const float* c2f = (const float*)d_in[2];
  const int* idx = (const int*)d_in[3];
  float* outf = (float*)d_out;
  const int B = in_sizes[3];  // 512
  dim3 grid(B * 8), block(256);
  hipLaunchKernelGGL(tt_stack_kernel, grid, block, 0, stream, c0f, c1f, c2f, idx, outf);
}